// Round 2
// baseline (5627.798 us; speedup 1.0000x reference)
//
#include <hip/hip_runtime.h>

#define B_ 64
#define S_ 512
#define I_ 512
#define H_ 1024
#define NBLK 128
#define OFF_H 33554432            // B_*S_*H_
#define OFF_C (33554432 + 65536)  // + B_*H_

typedef short bf16x8 __attribute__((ext_vector_type(8)));
typedef unsigned short u16x8 __attribute__((ext_vector_type(8)));
typedef float f32x4 __attribute__((ext_vector_type(4)));
typedef unsigned long long ull;

__device__ __forceinline__ unsigned short f2b(float f) {
  unsigned u = __float_as_uint(f);
  u += 0x7fffu + ((u >> 16) & 1u);   // RNE
  return (unsigned short)(u >> 16);
}
__device__ __forceinline__ float sigf(float x) { return 1.0f / (1.0f + __expf(-x)); }
__device__ __forceinline__ float tanh_(float x) { return 2.0f / (1.0f + __expf(-2.0f * x)) - 1.0f; }

// ---------- preamble: x -> bf16 ----------
__global__ __launch_bounds__(256) void k_cvt_x(const float* __restrict__ x,
                                               unsigned short* __restrict__ x16) {
  long long i = ((long long)blockIdx.x * 256 + threadIdx.x) * 8;
  float4 a = *(const float4*)(x + i);
  float4 b = *(const float4*)(x + i + 4);
  u16x8 o;
  o[0] = f2b(a.x); o[1] = f2b(a.y); o[2] = f2b(a.z); o[3] = f2b(a.w);
  o[4] = f2b(b.x); o[5] = f2b(b.y); o[6] = f2b(b.z); o[7] = f2b(b.w);
  *(u16x8*)(x16 + i) = o;
}

// ---------- preamble: W_x -> fragment-ordered bf16 [g][ct2][kc16][lane][8] ----------
__global__ __launch_bounds__(256) void k_wx(const float* __restrict__ Wx,
                                            unsigned short* __restrict__ wxf) {
  int gid = blockIdx.x * 256 + threadIdx.x;
  int lane = gid & 63, kc = (gid >> 6) & 15, ct = (gid >> 10) & 1, g = gid >> 11;
  int c = lane & 15, q = lane >> 4;
  int col = (ct * 2 + (c >> 3)) * H_ + g * 8 + (c & 7);  // gate-major column mapping
  int k0 = kc * 32 + q * 8;
  u16x8 o;
#pragma unroll
  for (int j = 0; j < 8; ++j) o[j] = f2b(Wx[(long long)(k0 + j) * (4 * H_) + col]);
  *(u16x8*)(wxf + (long long)gid * 8) = o;
}

// ---------- preamble: W_h -> fragment-ordered bf16 [g][ct2][kc32][lane][8] ----------
__global__ __launch_bounds__(256) void k_wh(const float* __restrict__ Wh,
                                            unsigned short* __restrict__ whf) {
  int gid = blockIdx.x * 256 + threadIdx.x;
  int lane = gid & 63, kc = (gid >> 6) & 31, ct = (gid >> 11) & 1, g = gid >> 12;
  int c = lane & 15, q = lane >> 4;
  int col = (ct * 2 + (c >> 3)) * H_ + g * 8 + (c & 7);
  int k0 = kc * 32 + q * 8;
  u16x8 o;
#pragma unroll
  for (int j = 0; j < 8; ++j) o[j] = f2b(Wh[(long long)(k0 + j) * (4 * H_) + col]);
  *(u16x8*)(whf + (long long)gid * 8) = o;
}

// ---------- persistent scan kernel: 128 blocks x 256 threads ----------
// Barrier-free dataflow (round 1) + PER-CONSUMER MAILBOX flags (round 2).
// Round-1 post-mortem: all ~512 polling waves spun on the same 2-8 cache
// lines of a shared flag array via L2-bypassing loads -> L3 hot-line
// queueing ~10us/step dominated. Fix: producers broadcast their epoch to
// mbox[consumer_g][wave][producer_g]; each consumer wave spins on a
// private 512B row (4 lines, single reader). Data remains self-validating
// (all-u32-nonzero granules in write-once per-step h regions), so no
// fences/drains/barriers are needed anywhere in the scan loop.
__global__ __launch_bounds__(256, 1) void k_scan(
    const unsigned short* __restrict__ x16, const unsigned short* __restrict__ wxf,
    const unsigned short* __restrict__ whf, const float* __restrict__ bias,
    unsigned short* __restrict__ hbuf, unsigned* __restrict__ mbox,
    float* __restrict__ out) {
  __shared__ unsigned short ldsWh[2 * 32 * 64 * 8];  // 64 KB, fragment order
  __shared__ unsigned short ldsWx[2 * 16 * 64 * 8];  // 32 KB, fragment order
  const int tid = threadIdx.x, g = blockIdx.x;

  for (int i = tid; i < 4096; i += 256)
    ((u16x8*)ldsWh)[i] = ((const u16x8*)(whf + (long long)g * 32768))[i];
  for (int i = tid; i < 2048; i += 256)
    ((u16x8*)ldsWx)[i] = ((const u16x8*)(wxf + (long long)g * 16384))[i];
  __syncthreads();  // the ONLY barrier; LDS is read-only afterwards

  const int wave = tid >> 6, lane = tid & 63;
  const int c = lane & 15, q = lane >> 4;
  const int rowA = wave * 16 + c;   // A-operand batch row
  const int kofs = q * 8;
  const int j = 8 * g + (c & 7);    // hidden index owned (lanes c<8)
  const float bias0 = bias[(c >> 3) * H_ + j];        // i (c<8) / f (c>=8)
  const float bias1 = bias[(2 + (c >> 3)) * H_ + j];  // g / o
  const int rowD = wave * 16 + q * 4;
  f32x4 cst = {0.f, 0.f, 0.f, 0.f};

  const unsigned short* xrow = x16 + (long long)rowA * (S_ * I_) + kofs;
  const ull* hrow = (const ull*)(hbuf + (long long)rowA * H_ + kofs);
  // private flag row for this consumer wave: mbox[g][wave][0..127]
  const unsigned* mb = mbox + (g * 4 + wave) * 128;
  // producer-side mailbox targets: this wave writes epoch to consumers
  // cg = lane and cg = lane+64 (one u32 each, fire-and-forget)
  unsigned* mw0 = mbox + (lane * 4 + wave) * 128 + g;
  unsigned* mw1 = mbox + ((lane + 64) * 4 + wave) * 128 + g;

  for (int t = 0; t < S_; ++t) {
    f32x4 a0 = {bias0, bias0, bias0, bias0};
    f32x4 a1 = {bias1, bias1, bias1, bias1};

    // ---- x-part: independent of h_t; overlaps peers' h_t propagation ----
    const unsigned short* xp = xrow + t * I_;
#pragma unroll
    for (int kc = 0; kc < 16; ++kc) {
      bf16x8 av = *(const bf16x8*)(xp + kc * 32);
      bf16x8 b0 = *(const bf16x8*)(ldsWx + kc * 512 + lane * 8);
      bf16x8 b1 = *(const bf16x8*)(ldsWx + (16 + kc) * 512 + lane * 8);
      a0 = __builtin_amdgcn_mfma_f32_16x16x32_bf16(av, b0, a0, 0, 0, 0);
      a1 = __builtin_amdgcn_mfma_f32_16x16x32_bf16(av, b1, a1, 0, 0, 0);
    }

    // ---- h-part: self-validating dataflow consumption (skip t=0: h_0=0) ----
    if (t > 0) {
      const ull* hq = hrow + (long long)t * 16384;  // region for h_t (u64 units)
      unsigned done = 0u;

      auto sweep = [&](unsigned todo) {
        ull hlo[32], hhi[32];
#pragma unroll
        for (int kc = 0; kc < 32; ++kc) {
          if (todo & (1u << kc)) {
            hlo[kc] = __hip_atomic_load(hq + kc * 8, __ATOMIC_RELAXED,
                                        __HIP_MEMORY_SCOPE_AGENT);
            hhi[kc] = __hip_atomic_load(hq + kc * 8 + 1, __ATOMIC_RELAXED,
                                        __HIP_MEMORY_SCOPE_AGENT);
          }
        }
#pragma unroll
        for (int kc = 0; kc < 32; ++kc) {
          if (todo & (1u << kc)) {
            ull l0 = hlo[kc], l1 = hhi[kc];
            int ok = ((unsigned)l0 != 0u) && ((unsigned)(l0 >> 32) != 0u) &&
                     ((unsigned)l1 != 0u) && ((unsigned)(l1 >> 32) != 0u);
            if (__all(ok)) {
              union { ull qw[2]; bf16x8 v; } u;
              u.qw[0] = l0; u.qw[1] = l1;
              bf16x8 av = u.v;
              bf16x8 b0 = *(const bf16x8*)(ldsWh + kc * 512 + lane * 8);
              bf16x8 b1 = *(const bf16x8*)(ldsWh + (32 + kc) * 512 + lane * 8);
              a0 = __builtin_amdgcn_mfma_f32_16x16x32_bf16(av, b0, a0, 0, 0, 0);
              a1 = __builtin_amdgcn_mfma_f32_16x16x32_bf16(av, b1, a1, 0, 0, 0);
              done |= 1u << kc;
            }
          }
        }
      };

      // speculative first sweep: zero added latency when peers are ahead
      sweep(0xffffffffu);

      // laggards: poll PRIVATE mailbox row (4 lines, single reader), then
      // gated reload of only the newly-ready chunks
      while (done != 0xffffffffu) {
        const unsigned tgt = (unsigned)t;
        unsigned f0 = __hip_atomic_load(mb + lane, __ATOMIC_RELAXED,
                                        __HIP_MEMORY_SCOPE_AGENT);
        unsigned f1 = __hip_atomic_load(mb + 64 + lane, __ATOMIC_RELAXED,
                                        __HIP_MEMORY_SCOPE_AGENT);
        ull m0 = __ballot(f0 >= tgt);   // producers 0..63  -> chunks 0..15
        ull m1 = __ballot(f1 >= tgt);   // producers 64..127 -> chunks 16..31
        m0 &= (m0 >> 1) & (m0 >> 2) & (m0 >> 3);  // bit 4k = chunk k's 4 producers done
        m1 &= (m1 >> 1) & (m1 >> 2) & (m1 >> 3);
        unsigned hint = 0;
#pragma unroll
        for (int i = 0; i < 16; ++i) {
          hint |= (unsigned)((m0 >> (4 * i)) & 1ull) << i;
          hint |= (unsigned)((m1 >> (4 * i)) & 1ull) << (16 + i);
        }
        unsigned todo = hint & ~done;
        if (todo) sweep(todo);
      }
    }

    // ---- elementwise LSTM update (lane c pairs with lane c+8) ----
    f32x4 h4;
#pragma unroll
    for (int r = 0; r < 4; ++r) {
      float fg = __shfl_xor(a0[r], 8, 64);  // f at lanes c<8
      float og = __shfl_xor(a1[r], 8, 64);  // o at lanes c<8
      float iv = sigf(a0[r]);
      float fv = sigf(fg);
      float gv = tanh_(a1[r]);
      float ov = sigf(og);
      float cv = fv * cst[r] + iv * gv;
      cst[r] = cv;
      h4[r] = ov * tanh_(cv);
    }

    // ---- publish h_{t+1} into its fresh region (no drain, no barrier) ----
    if (c < 8) {
      unsigned short* hw = hbuf + (long long)(t + 1) * (B_ * H_);
#pragma unroll
      for (int r = 0; r < 4; ++r) {
        int b = rowD + r;
        unsigned short hb = f2b(h4[r]);
        if (hb == 0) hb = 0x8000;  // +0.0 -> -0.0: exact, keeps token nonzero
        unsigned pv = (unsigned)__shfl_xor((int)hb, 1, 64) & 0xffffu;
        if ((c & 1) == 0) {
          __hip_atomic_store((unsigned*)(hw + b * H_ + j),
                             ((unsigned)hb) | (pv << 16), __ATOMIC_RELAXED,
                             __HIP_MEMORY_SCOPE_AGENT);
        }
      }
    }
    // mailbox broadcast: each lane posts this wave's epoch to 2 consumers.
    // Relaxed, posted after h stores in program order; consumers validate
    // data anyway, so no vmcnt drain is required.
    {
      unsigned e = (unsigned)(t + 1);
      __hip_atomic_store(mw0, e, __ATOMIC_RELAXED, __HIP_MEMORY_SCOPE_AGENT);
      __hip_atomic_store(mw1, e, __ATOMIC_RELAXED, __HIP_MEMORY_SCOPE_AGENT);
    }

    // ---- out f32 stores AFTER publish: fully off the critical path ----
    if (c < 8) {
#pragma unroll
      for (int r = 0; r < 4; ++r) {
        int b = rowD + r;
        out[((long long)b * S_ + t) * H_ + j] = h4[r];
      }
      if (t == S_ - 1) {
#pragma unroll
        for (int r = 0; r < 4; ++r) {
          int b = rowD + r;
          out[OFF_H + b * H_ + j] = h4[r];
          out[OFF_C + b * H_ + j] = cst[r];
        }
      }
    }
  }
}

extern "C" void kernel_launch(void* const* d_in, const int* in_sizes, int n_in,
                              void* d_out, int out_size, void* d_ws, size_t ws_size,
                              hipStream_t stream) {
  const float* x = (const float*)d_in[0];
  const float* Wx = (const float*)d_in[1];
  const float* Wh = (const float*)d_in[2];
  const float* bias = (const float*)d_in[3];
  float* out = (float*)d_out;
  char* ws = (char*)d_ws;

  // ws layout (bytes):
  //   [0, 262144)               mbox u32[128 consumers][4 waves][128 producers]
  //   [262144, 67502080)        h regions, bf16 [513][64][1024] (write-once per step)
  //   [67502080, 101056512)     x16 bf16 (33.5 MB)
  //   [101056512, 105250816)    wxf fragment-ordered W_x bf16 (4 MB)
  //   [105250816, 113639424)    whf fragment-ordered W_h bf16 (8 MB)  total ~113.6 MB
  unsigned* mbox = (unsigned*)ws;
  unsigned short* hbuf = (unsigned short*)(ws + 262144);
  unsigned short* x16 = (unsigned short*)(ws + 67502080);
  unsigned short* wxf = (unsigned short*)(ws + 101056512);
  unsigned short* whf = (unsigned short*)(ws + 105250816);

  // zero mailboxes + all h regions (validity tokens rely on zero-init each run)
  hipMemsetAsync(ws, 0, 67502080, stream);
  hipLaunchKernelGGL(k_cvt_x, dim3(8192), dim3(256), 0, stream, x, x16);
  hipLaunchKernelGGL(k_wx, dim3(1024), dim3(256), 0, stream, Wx, wxf);
  hipLaunchKernelGGL(k_wh, dim3(2048), dim3(256), 0, stream, Wh, whf);
  hipLaunchKernelGGL(k_scan, dim3(NBLK), dim3(256), 0, stream, x16, wxf, whf, bias,
                     hbuf, mbox, out);
  (void)in_sizes; (void)n_in; (void)out_size; (void)ws_size;
}

// Round 3
// 4335.846 us; speedup vs baseline: 1.2980x; 1.2980x over previous
//
#include <hip/hip_runtime.h>

#define B_ 64
#define S_ 512
#define I_ 512
#define H_ 1024
#define NBLK 128
#define OFF_H 33554432            // B_*S_*H_
#define OFF_C (33554432 + 65536)  // + B_*H_

typedef short bf16x8 __attribute__((ext_vector_type(8)));
typedef unsigned short u16x8 __attribute__((ext_vector_type(8)));
typedef float f32x4 __attribute__((ext_vector_type(4)));
typedef unsigned long long ull;

__device__ __forceinline__ unsigned short f2b(float f) {
  unsigned u = __float_as_uint(f);
  u += 0x7fffu + ((u >> 16) & 1u);   // RNE
  return (unsigned short)(u >> 16);
}
__device__ __forceinline__ float sigf(float x) { return 1.0f / (1.0f + __expf(-x)); }
__device__ __forceinline__ float tanh_(float x) { return 2.0f / (1.0f + __expf(-2.0f * x)) - 1.0f; }

// ---------- preamble: x -> bf16 ----------
__global__ __launch_bounds__(256) void k_cvt_x(const float* __restrict__ x,
                                               unsigned short* __restrict__ x16) {
  long long i = ((long long)blockIdx.x * 256 + threadIdx.x) * 8;
  float4 a = *(const float4*)(x + i);
  float4 b = *(const float4*)(x + i + 4);
  u16x8 o;
  o[0] = f2b(a.x); o[1] = f2b(a.y); o[2] = f2b(a.z); o[3] = f2b(a.w);
  o[4] = f2b(b.x); o[5] = f2b(b.y); o[6] = f2b(b.z); o[7] = f2b(b.w);
  *(u16x8*)(x16 + i) = o;
}

// ---------- preamble: W_x -> fragment-ordered bf16 [g][ct2][kc16][lane][8] ----------
__global__ __launch_bounds__(256) void k_wx(const float* __restrict__ Wx,
                                            unsigned short* __restrict__ wxf) {
  int gid = blockIdx.x * 256 + threadIdx.x;
  int lane = gid & 63, kc = (gid >> 6) & 15, ct = (gid >> 10) & 1, g = gid >> 11;
  int c = lane & 15, q = lane >> 4;
  int col = (ct * 2 + (c >> 3)) * H_ + g * 8 + (c & 7);  // gate-major column mapping
  int k0 = kc * 32 + q * 8;
  u16x8 o;
#pragma unroll
  for (int j = 0; j < 8; ++j) o[j] = f2b(Wx[(long long)(k0 + j) * (4 * H_) + col]);
  *(u16x8*)(wxf + (long long)gid * 8) = o;
}

// ---------- preamble: W_h -> fragment-ordered bf16 [g][ct2][kc32][lane][8] ----------
__global__ __launch_bounds__(256) void k_wh(const float* __restrict__ Wh,
                                            unsigned short* __restrict__ whf) {
  int gid = blockIdx.x * 256 + threadIdx.x;
  int lane = gid & 63, kc = (gid >> 6) & 31, ct = (gid >> 11) & 1, g = gid >> 12;
  int c = lane & 15, q = lane >> 4;
  int col = (ct * 2 + (c >> 3)) * H_ + g * 8 + (c & 7);
  int k0 = kc * 32 + q * 8;
  u16x8 o;
#pragma unroll
  for (int j = 0; j < 8; ++j) o[j] = f2b(Wh[(long long)(k0 + j) * (4 * H_) + col]);
  *(u16x8*)(whf + (long long)gid * 8) = o;
}

// ---------- persistent scan kernel: 128 blocks x 256 threads ----------
// Round-3: L2-ROUTED h FAN-OUT. Rounds 0-2 all burned ~10us/step because
// every consumer read full h_t via L2-bypassing agent loads -> ~16-32 MB
// of scattered L3 requests per step (L3 request-rate wall). Now h loads
// are NORMAL cached loads: the 16 blocks sharing an XCD hit their L2
// after the first toucher pulls the line from L3 (16x L3 traffic cut).
// Safety: loads are STRICTLY flag-gated (no speculation -> an h line is
// only ever cached post-publish), each step's h is a write-once region
// (never in any L2 beforehand; dispatch invalidates L2 across launches),
// and producers order data->flag via s_waitcnt vmcnt(0). Flags stay
// agent-scope (always L3-fresh). Waves are fully decoupled (4 independent
// wave-planes per block, no __syncthreads in the loop).
__global__ __launch_bounds__(256, 1) void k_scan(
    const unsigned short* __restrict__ x16, const unsigned short* __restrict__ wxf,
    const unsigned short* __restrict__ whf, const float* __restrict__ bias,
    unsigned short* __restrict__ hbuf, unsigned* __restrict__ flags,
    float* __restrict__ out) {
  __shared__ unsigned short ldsWh[2 * 32 * 64 * 8];  // 64 KB, fragment order
  __shared__ unsigned short ldsWx[2 * 16 * 64 * 8];  // 32 KB, fragment order
  const int tid = threadIdx.x, g = blockIdx.x;

  for (int i = tid; i < 4096; i += 256)
    ((u16x8*)ldsWh)[i] = ((const u16x8*)(whf + (long long)g * 32768))[i];
  for (int i = tid; i < 2048; i += 256)
    ((u16x8*)ldsWx)[i] = ((const u16x8*)(wxf + (long long)g * 16384))[i];
  __syncthreads();  // the ONLY barrier; LDS is read-only afterwards

  const int wave = tid >> 6, lane = tid & 63;
  const int c = lane & 15, q = lane >> 4;
  const int rowA = wave * 16 + c;   // A-operand batch row
  const int kofs = q * 8;
  const int j = 8 * g + (c & 7);    // hidden index owned (lanes c<8)
  const float bias0 = bias[(c >> 3) * H_ + j];        // i (c<8) / f (c>=8)
  const float bias1 = bias[(2 + (c >> 3)) * H_ + j];  // g / o
  const int rowD = wave * 16 + q * 4;
  f32x4 cst = {0.f, 0.f, 0.f, 0.f};

  const unsigned short* xrow = x16 + (long long)rowA * (S_ * I_) + kofs;
  const ull* hrow = (const ull*)(hbuf + (long long)rowA * H_ + kofs);
  const unsigned* fl = flags + wave * 128;  // this wave-plane's flag row

  for (int t = 0; t < S_; ++t) {
    f32x4 a0 = {bias0, bias0, bias0, bias0};
    f32x4 a1 = {bias1, bias1, bias1, bias1};

    // ---- x-part: independent of h_t; overlaps peers' h_t propagation ----
    const unsigned short* xp = xrow + t * I_;
#pragma unroll
    for (int kc = 0; kc < 16; ++kc) {
      bf16x8 av = *(const bf16x8*)(xp + kc * 32);
      bf16x8 b0 = *(const bf16x8*)(ldsWx + kc * 512 + lane * 8);
      bf16x8 b1 = *(const bf16x8*)(ldsWx + (16 + kc) * 512 + lane * 8);
      a0 = __builtin_amdgcn_mfma_f32_16x16x32_bf16(av, b0, a0, 0, 0, 0);
      a1 = __builtin_amdgcn_mfma_f32_16x16x32_bf16(av, b1, a1, 0, 0, 0);
    }

    // ---- h-part: strictly flag-gated, L2-cached consumption (t=0: h_0=0) ----
    if (t > 0) {
      const ull* hq = hrow + (long long)t * 16384;  // write-once region for h_t
      unsigned done = 0u;
      const unsigned tgt = (unsigned)t;

      while (done != 0xffffffffu) {
        // poll agent-scope flags (always fresh from L3)
        unsigned f0 = __hip_atomic_load(fl + lane, __ATOMIC_RELAXED,
                                        __HIP_MEMORY_SCOPE_AGENT);
        unsigned f1 = __hip_atomic_load(fl + 64 + lane, __ATOMIC_RELAXED,
                                        __HIP_MEMORY_SCOPE_AGENT);
        ull m0 = __ballot(f0 >= tgt);   // producers 0..63  -> chunks 0..15
        ull m1 = __ballot(f1 >= tgt);   // producers 64..127 -> chunks 16..31
        m0 &= (m0 >> 1) & (m0 >> 2) & (m0 >> 3);  // chunk ready = its 4 producers done
        m1 &= (m1 >> 1) & (m1 >> 2) & (m1 >> 3);
        unsigned hint = 0;
#pragma unroll
        for (int i = 0; i < 16; ++i) {
          hint |= (unsigned)((m0 >> (4 * i)) & 1ull) << i;
          hint |= (unsigned)((m1 >> (4 * i)) & 1ull) << (16 + i);
        }
        unsigned todo = hint & ~done;
        if (todo) {
          // keep the cached loads below from hoisting above the flag poll
          asm volatile("" ::: "memory");
          ull hlo[32], hhi[32];
#pragma unroll
          for (int kc = 0; kc < 32; ++kc) {
            if (todo & (1u << kc)) {
              hlo[kc] = hq[kc * 8];       // NORMAL load: L2-shared across XCD
              hhi[kc] = hq[kc * 8 + 1];
            }
          }
#pragma unroll
          for (int kc = 0; kc < 32; ++kc) {
            if (todo & (1u << kc)) {
              union { ull qw[2]; bf16x8 v; } u;
              u.qw[0] = hlo[kc]; u.qw[1] = hhi[kc];
              bf16x8 av = u.v;
              bf16x8 b0 = *(const bf16x8*)(ldsWh + kc * 512 + lane * 8);
              bf16x8 b1 = *(const bf16x8*)(ldsWh + (32 + kc) * 512 + lane * 8);
              a0 = __builtin_amdgcn_mfma_f32_16x16x32_bf16(av, b0, a0, 0, 0, 0);
              a1 = __builtin_amdgcn_mfma_f32_16x16x32_bf16(av, b1, a1, 0, 0, 0);
            }
          }
          done |= todo;
        }
      }
    }

    // ---- elementwise LSTM update (lane c pairs with lane c+8) ----
    f32x4 h4;
#pragma unroll
    for (int r = 0; r < 4; ++r) {
      float fg = __shfl_xor(a0[r], 8, 64);  // f at lanes c<8
      float og = __shfl_xor(a1[r], 8, 64);  // o at lanes c<8
      float iv = sigf(a0[r]);
      float fv = sigf(fg);
      float gv = tanh_(a1[r]);
      float ov = sigf(og);
      float cv = fv * cst[r] + iv * gv;
      cst[r] = cv;
      h4[r] = ov * tanh_(cv);
    }

    // ---- publish h_{t+1}: agent stores (bypass own L2, land in L3) ----
    if (c < 8) {
      unsigned short* hw = hbuf + (long long)(t + 1) * (B_ * H_);
#pragma unroll
      for (int r = 0; r < 4; ++r) {
        int b = rowD + r;
        unsigned short hb = f2b(h4[r]);
        unsigned pv = (unsigned)__shfl_xor((int)hb, 1, 64) & 0xffffu;
        if ((c & 1) == 0) {
          __hip_atomic_store((unsigned*)(hw + b * H_ + j),
                             ((unsigned)hb) | (pv << 16), __ATOMIC_RELAXED,
                             __HIP_MEMORY_SCOPE_AGENT);
        }
      }
    }
    // order data -> flag: wait for the h stores to reach the coherence
    // point, THEN publish the per-wave epoch flag (consumers gate on it).
    asm volatile("s_waitcnt vmcnt(0)" ::: "memory");
    if (lane == 0)
      __hip_atomic_store((unsigned*)(flags + wave * 128 + g), (unsigned)(t + 1),
                         __ATOMIC_RELAXED, __HIP_MEMORY_SCOPE_AGENT);

    // ---- out f32 stores AFTER publish: fully off the critical path ----
    if (c < 8) {
#pragma unroll
      for (int r = 0; r < 4; ++r) {
        int b = rowD + r;
        out[((long long)b * S_ + t) * H_ + j] = h4[r];
      }
      if (t == S_ - 1) {
#pragma unroll
        for (int r = 0; r < 4; ++r) {
          int b = rowD + r;
          out[OFF_H + b * H_ + j] = h4[r];
          out[OFF_C + b * H_ + j] = cst[r];
        }
      }
    }
  }
}

extern "C" void kernel_launch(void* const* d_in, const int* in_sizes, int n_in,
                              void* d_out, int out_size, void* d_ws, size_t ws_size,
                              hipStream_t stream) {
  const float* x = (const float*)d_in[0];
  const float* Wx = (const float*)d_in[1];
  const float* Wh = (const float*)d_in[2];
  const float* bias = (const float*)d_in[3];
  float* out = (float*)d_out;
  char* ws = (char*)d_ws;

  // ws layout (bytes):
  //   [0, 2048)                 flags u32[4 waves][128 producers]
  //   [4096, 67244032)          h regions, bf16 [513][64][1024] (write-once per step)
  //   [67244032, 100798464)     x16 bf16 (33.5 MB)
  //   [100798464, 104992768)    wxf fragment-ordered W_x bf16 (4 MB)
  //   [104992768, 113381376)    whf fragment-ordered W_h bf16 (8 MB)  total ~113.4 MB
  unsigned* flags = (unsigned*)ws;
  unsigned short* hbuf = (unsigned short*)(ws + 4096);
  unsigned short* x16 = (unsigned short*)(ws + 67244032);
  unsigned short* wxf = (unsigned short*)(ws + 100798464);
  unsigned short* whf = (unsigned short*)(ws + 104992768);

  // zero ONLY the flags (h regions are strictly flag-gated; no tokens)
  hipMemsetAsync(ws, 0, 4096, stream);
  hipLaunchKernelGGL(k_cvt_x, dim3(8192), dim3(256), 0, stream, x, x16);
  hipLaunchKernelGGL(k_wx, dim3(1024), dim3(256), 0, stream, Wx, wxf);
  hipLaunchKernelGGL(k_wh, dim3(2048), dim3(256), 0, stream, Wh, whf);
  hipLaunchKernelGGL(k_scan, dim3(NBLK), dim3(256), 0, stream, x16, wxf, whf, bias,
                     hbuf, flags, out);
  (void)in_sizes; (void)n_in; (void)out_size; (void)ws_size;
}